// Round 3
// baseline (157.804 us; speedup 1.0000x reference)
//
#include <hip/hip_runtime.h>
#include <hip/hip_bf16.h>
#include <cstdint>

#define HDIM 1024
#define BM 256
#define BN 64
#define BKK 32
#define NT (HDIM / BKK)   // 32 K-tiles

typedef __attribute__((ext_vector_type(8))) __bf16 bf16x8;
typedef __attribute__((ext_vector_type(8))) unsigned short u16x8;
typedef __attribute__((ext_vector_type(4))) float f32x4;

static __device__ __forceinline__ unsigned short f2b(float f) {
    __hip_bfloat16 h = __float2bfloat16(f);
    return __builtin_bit_cast(unsigned short, h);
}

static __device__ __forceinline__ void barrier_fence() {
    asm volatile("" ::: "memory");
    __builtin_amdgcn_s_barrier();
    asm volatile("" ::: "memory");
}

// fp32 -> bf16 pack: weights (+ x,h when ws allows)
__global__ void __launch_bounds__(256) cvt_all(
    const float* __restrict__ x, const float* __restrict__ h,
    const float* __restrict__ wih, const float* __restrict__ ur,
    const float* __restrict__ uz, const float* __restrict__ un,
    unsigned short* __restrict__ wb, unsigned short* __restrict__ urb,
    unsigned short* __restrict__ uzb, unsigned short* __restrict__ unb,
    unsigned short* __restrict__ xb, unsigned short* __restrict__ hb) {
    int b = blockIdx.x;
    const float* src; unsigned short* dst; int idx;
    if (b < 3072)       { src = wih; dst = wb;  idx = b; }
    else if (b < 4096)  { src = ur;  dst = urb; idx = b - 3072; }
    else if (b < 5120)  { src = uz;  dst = uzb; idx = b - 4096; }
    else if (b < 6144)  { src = un;  dst = unb; idx = b - 5120; }
    else if (b < 14336) { src = x;   dst = xb;  idx = b - 6144; }
    else                { src = h;   dst = hb;  idx = b - 14336; }
    int i = idx * 256 + threadIdx.x;
    float4 v = ((const float4*)src)[i];
    ushort4 o;
    o.x = f2b(v.x); o.y = f2b(v.y); o.z = f2b(v.z); o.w = f2b(v.w);
    ((ushort4*)dst)[i] = o;
}

// gate map: mi 0(Wr),3(Ur)->acc0 ; 1(Wz),4(Uz)->acc1 ; 2(Wn)->acc2 ; 5(Un)->acc3
template<int MH, int NF>
__device__ __forceinline__ void mm_cluster(f32x4 (&acc)[4][4][2],
        const bf16x8 (&ax)[4], const bf16x8 (&ah)[4], const bf16x8 (&bq)[6]) {
#pragma unroll
    for (int mi = 0; mi < 6; ++mi) {
        const int g = (mi == 0 || mi == 3) ? 0 : (mi == 1 || mi == 4) ? 1 : (mi == 2) ? 2 : 3;
#pragma unroll
        for (int m2 = 0; m2 < 2; ++m2) {
            const int mf = MH * 2 + m2;
            acc[g][mf][NF] = __builtin_amdgcn_mfma_f32_16x16x32_bf16(
                (mi < 3) ? ax[mf] : ah[mf], bq[mi], acc[g][mf][NF], 0, 0, 0);
        }
    }
}

// 8-wave, 4-phase-per-K-tile GRU cell. Block = 256x64 output, waves 4M x 2N.
// LDS per buffer (ushorts): xs[0,8192) hs[8192,16384) w[mi]@16384+mi*2048. 2 buffers.
// Swizzle (both sides): 16B slot s of row r lives at s ^ ((r>>1)&3).
__global__ void __launch_bounds__(512, 2)
gru_fused8(const float* __restrict__ hg,
           const unsigned short* __restrict__ xb, const unsigned short* __restrict__ hb,
           const unsigned short* __restrict__ wih,
           const unsigned short* __restrict__ ur,
           const unsigned short* __restrict__ uz,
           const unsigned short* __restrict__ un,
           const float* __restrict__ bih, const float* __restrict__ bun,
           float* __restrict__ out) {
    __shared__ __align__(16) unsigned short smem[2][28672];

    const int tid  = threadIdx.x;
    const int lane = tid & 63;
    const int wv   = tid >> 6;      // 0..7
    const int wm   = wv >> 1;       // 0..3 (M quadrant, 64 rows)
    const int wn   = wv & 1;        // 0..1 (N half, 32 cols)
    const int lr   = lane & 15;
    const int ls   = lane >> 4;
    const int sel  = (lr >> 1) & 3;
    const int fo   = (ls ^ sel) << 3;     // swizzled 16B slot (in ushorts)

    // XCD-aware swizzle: 512 blocks, %8==0 -> simple bijective form
    const int bid = blockIdx.x;
    const int swz = (bid & 7) * 64 + (bid >> 3);
    const int m0  = (swz & 31) * BM;
    const int n0  = (swz >> 5) * BN;

    const unsigned short* wb6[6] = {
        wih + (size_t)n0 * HDIM,
        wih + (size_t)(HDIM + n0) * HDIM,
        wih + (size_t)(2 * HDIM + n0) * HDIM,
        ur  + (size_t)n0 * HDIM,
        uz  + (size_t)n0 * HDIM,
        un  + (size_t)n0 * HDIM
    };

    f32x4 acc[4][4][2];
#pragma unroll
    for (int g = 0; g < 4; ++g)
#pragma unroll
        for (int mf = 0; mf < 4; ++mf)
#pragma unroll
            for (int nf = 0; nf < 2; ++nf)
                acc[g][mf][nf] = f32x4{0.f, 0.f, 0.f, 0.f};

    // ---- staging: 7 gload_lds / thread / K-tile (3 w, 2 x, 2 h)
    auto STAGE_W = [&](unsigned short* nb, int kt) {
        const int k0 = kt * BKK;
#pragma unroll
        for (int l = 0; l < 3; ++l) {
            const int id = l * 512 + tid;          // 0..1535 over 6 tiles
            const int mi = id >> 8;
            const int c  = id & 255;
            const int r  = c >> 2;
            const int sl = (c & 3) ^ ((c >> 3) & 3);
            const unsigned short* g = wb6[mi] + (size_t)r * HDIM + k0 + sl * 8;
            __builtin_amdgcn_global_load_lds(
                (const __attribute__((address_space(1))) void*)g,
                (__attribute__((address_space(3))) void*)(nb + 16384 + l * 4096 + wv * 512),
                16, 0, 0);
        }
    };
    auto STAGE_X = [&](unsigned short* nb, int kt) {
        const int k0 = kt * BKK;
#pragma unroll
        for (int half = 0; half < 2; ++half) {
            const int c  = half * 512 + tid;       // 0..1023 chunks (256 rows x 4 slots)
            const int r  = c >> 2;
            const int sl = (c & 3) ^ ((c >> 3) & 3);
            const unsigned short* g = xb + (size_t)(m0 + r) * HDIM + k0 + sl * 8;
            __builtin_amdgcn_global_load_lds(
                (const __attribute__((address_space(1))) void*)g,
                (__attribute__((address_space(3))) void*)(nb + half * 4096 + wv * 512),
                16, 0, 0);
        }
    };
    auto STAGE_H = [&](unsigned short* nb, int kt) {
        const int k0 = kt * BKK;
#pragma unroll
        for (int half = 0; half < 2; ++half) {
            const int c  = half * 512 + tid;
            const int r  = c >> 2;
            const int sl = (c & 3) ^ ((c >> 3) & 3);
            const unsigned short* g = hb + (size_t)(m0 + r) * HDIM + k0 + sl * 8;
            __builtin_amdgcn_global_load_lds(
                (const __attribute__((address_space(1))) void*)g,
                (__attribute__((address_space(3))) void*)(nb + 8192 + half * 4096 + wv * 512),
                16, 0, 0);
        }
    };

    auto TILE = [&](int cur, int ktn, bool stage) {
        const unsigned short* sb = &smem[cur][0];
        unsigned short* nb = &smem[cur ^ 1][0];
        bf16x8 ax[4], ah[4], bq[6];

        // ---- P0: read B[nf=0] (6) + A[mh=0] (4) | stage weights
        {
            const int ra0 = (wm * 64 + 0 * 16 + lr) * 32 + fo;
            const int ra1 = (wm * 64 + 1 * 16 + lr) * 32 + fo;
            ax[0] = *(const bf16x8*)(sb + ra0);
            ah[0] = *(const bf16x8*)(sb + 8192 + ra0);
            ax[1] = *(const bf16x8*)(sb + ra1);
            ah[1] = *(const bf16x8*)(sb + 8192 + ra1);
            const int rb = (wn * 32 + 0 * 16 + lr) * 32 + fo;
#pragma unroll
            for (int mi = 0; mi < 6; ++mi)
                bq[mi] = *(const bf16x8*)(sb + 16384 + mi * 2048 + rb);
        }
        if (stage) STAGE_W(nb, ktn);
        barrier_fence();
        asm volatile("s_waitcnt lgkmcnt(0)" ::: "memory");
        __builtin_amdgcn_sched_barrier(0);
        __builtin_amdgcn_s_setprio(1);
        mm_cluster<0, 0>(acc, ax, ah, bq);
        __builtin_amdgcn_s_setprio(0);
        barrier_fence();

        // ---- P1: read A[mh=1] (4) | stage x
        {
            const int ra2 = (wm * 64 + 2 * 16 + lr) * 32 + fo;
            const int ra3 = (wm * 64 + 3 * 16 + lr) * 32 + fo;
            ax[2] = *(const bf16x8*)(sb + ra2);
            ah[2] = *(const bf16x8*)(sb + 8192 + ra2);
            ax[3] = *(const bf16x8*)(sb + ra3);
            ah[3] = *(const bf16x8*)(sb + 8192 + ra3);
        }
        if (stage) STAGE_X(nb, ktn);
        barrier_fence();
        asm volatile("s_waitcnt lgkmcnt(0)" ::: "memory");
        __builtin_amdgcn_sched_barrier(0);
        __builtin_amdgcn_s_setprio(1);
        mm_cluster<1, 0>(acc, ax, ah, bq);
        __builtin_amdgcn_s_setprio(0);
        barrier_fence();

        // ---- P2: read B[nf=1] (6) | stage h
        {
            const int rb = (wn * 32 + 1 * 16 + lr) * 32 + fo;
#pragma unroll
            for (int mi = 0; mi < 6; ++mi)
                bq[mi] = *(const bf16x8*)(sb + 16384 + mi * 2048 + rb);
        }
        if (stage) STAGE_H(nb, ktn);
        barrier_fence();
        asm volatile("s_waitcnt lgkmcnt(0)" ::: "memory");
        __builtin_amdgcn_sched_barrier(0);
        __builtin_amdgcn_s_setprio(1);
        mm_cluster<0, 1>(acc, ax, ah, bq);
        __builtin_amdgcn_s_setprio(0);
        barrier_fence();

        // ---- P3: pure MFMA, then once-per-tile vmcnt drain of next tile's loads
        __builtin_amdgcn_s_setprio(1);
        mm_cluster<1, 1>(acc, ax, ah, bq);
        __builtin_amdgcn_s_setprio(0);
        asm volatile("s_waitcnt vmcnt(0)" ::: "memory");
        barrier_fence();
    };

    // prologue: stage tile 0, drain, sync
    STAGE_W(&smem[0][0], 0);
    STAGE_X(&smem[0][0], 0);
    STAGE_H(&smem[0][0], 0);
    asm volatile("s_waitcnt vmcnt(0)" ::: "memory");
    barrier_fence();

#pragma unroll 1
    for (int t = 0; t < NT - 1; ++t)
        TILE(t & 1, t + 1, true);
    TILE((NT - 1) & 1, 0, false);

    // epilogue: gates + output (C/D: col=lane&15, row=(lane>>4)*4+reg)
#pragma unroll
    for (int nf = 0; nf < 2; ++nf) {
        const int gc = n0 + wn * 32 + nf * 16 + lr;
        const float br  = bih[gc];
        const float bz  = bih[HDIM + gc];
        const float bnx = bih[2 * HDIM + gc];
        const float bn2 = bun[gc];
#pragma unroll
        for (int mf = 0; mf < 4; ++mf) {
#pragma unroll
            for (int rr = 0; rr < 4; ++rr) {
                const int gr = m0 + wm * 64 + mf * 16 + ls * 4 + rr;
                const float rv = 1.f / (1.f + __expf(-(acc[0][mf][nf][rr] + br)));
                const float zv = 1.f / (1.f + __expf(-(acc[1][mf][nf][rr] + bz)));
                const float nv = tanhf(acc[2][mf][nf][rr] + bnx + rv * (acc[3][mf][nf][rr] + bn2));
                const float hv = hg[(size_t)gr * HDIM + gc];
                out[(size_t)gr * HDIM + gc] = (1.f - zv) * nv + zv * hv;
            }
        }
    }
}

// ---------- fallback (ws too small for bf16 x/h): R2's proven 4-wave kernel ----------
__global__ void __launch_bounds__(256, 2)
gru_fused_fb(const float* __restrict__ hg,
             const float* __restrict__ xg32, const float* __restrict__ hg32,
             const unsigned short* __restrict__ wih,
             const unsigned short* __restrict__ ur,
             const unsigned short* __restrict__ uz,
             const unsigned short* __restrict__ un,
             const float* __restrict__ bih, const float* __restrict__ bun,
             float* __restrict__ out) {
    __shared__ __align__(16) unsigned short smem[2][20480];
    const int tid  = threadIdx.x;
    const int lane = tid & 63;
    const int wv   = tid >> 6;
    const int wm   = wv >> 1;
    const int wn   = wv & 1;
    const int lr   = lane & 15;
    const int ls   = lane >> 4;
    const int m0   = blockIdx.y * 128;
    const int n0   = blockIdx.x * BN;

    const unsigned short* wb6[6] = {
        wih + (size_t)n0 * HDIM, wih + (size_t)(HDIM + n0) * HDIM,
        wih + (size_t)(2 * HDIM + n0) * HDIM, ur + (size_t)n0 * HDIM,
        uz + (size_t)n0 * HDIM, un + (size_t)n0 * HDIM
    };
    const int wr  = tid >> 2;
    const int wsl = (tid & 3) ^ ((tid >> 3) & 3);

    f32x4 acc[4][4][2];
#pragma unroll
    for (int g = 0; g < 4; ++g)
#pragma unroll
        for (int mf = 0; mf < 4; ++mf)
#pragma unroll
            for (int nf = 0; nf < 2; ++nf)
                acc[g][mf][nf] = f32x4{0.f, 0.f, 0.f, 0.f};

    auto STAGE = [&](int bufi, int kt) {
        const int k0 = kt * BKK;
        unsigned short* sb = &smem[bufi][0];
        float4 fx[2][2], fh[2][2];
#pragma unroll
        for (int half = 0; half < 2; ++half) {
            const int c2 = half * 256 + tid;
            const int r2 = c2 >> 2;
            const int sl = c2 & 3;
            const float* gx = xg32 + (size_t)(m0 + r2) * HDIM + k0 + sl * 8;
            const float* gh = hg32 + (size_t)(m0 + r2) * HDIM + k0 + sl * 8;
            fx[half][0] = ((const float4*)gx)[0];
            fx[half][1] = ((const float4*)gx)[1];
            fh[half][0] = ((const float4*)gh)[0];
            fh[half][1] = ((const float4*)gh)[1];
        }
#pragma unroll
        for (int mi = 0; mi < 6; ++mi) {
            const unsigned short* g = wb6[mi] + (size_t)wr * HDIM + k0 + wsl * 8;
            __builtin_amdgcn_global_load_lds(
                (const __attribute__((address_space(1))) void*)g,
                (__attribute__((address_space(3))) void*)(sb + 8192 + mi * 2048 + wv * 512),
                16, 0, 0);
        }
#pragma unroll
        for (int half = 0; half < 2; ++half) {
            const int c2 = half * 256 + tid;
            const int r2 = c2 >> 2;
            const int sp = (c2 & 3) ^ ((c2 >> 3) & 3);
            u16x8 px, ph;
#pragma unroll
            for (int q = 0; q < 4; ++q) {
                px[q]     = f2b(fx[half][0][q]);
                px[q + 4] = f2b(fx[half][1][q]);
                ph[q]     = f2b(fh[half][0][q]);
                ph[q + 4] = f2b(fh[half][1][q]);
            }
            *(u16x8*)(sb + r2 * 32 + sp * 8)        = px;
            *(u16x8*)(sb + 4096 + r2 * 32 + sp * 8) = ph;
        }
    };
    auto COMPUTE = [&](int bufi) {
        const unsigned short* sb = &smem[bufi][0];
        const int sel = (lr >> 1) & 3;
        const int fo  = (ls ^ sel) << 3;
        bf16x8 ax[4], ah[4];
#pragma unroll
        for (int mf = 0; mf < 4; ++mf) {
            const int row = wm * 64 + mf * 16 + lr;
            ax[mf] = *(const bf16x8*)(sb + row * 32 + fo);
            ah[mf] = *(const bf16x8*)(sb + 4096 + row * 32 + fo);
        }
#pragma unroll
        for (int mi = 0; mi < 6; ++mi) {
            const unsigned short* wt = sb + 8192 + mi * 2048;
            bf16x8 b0 = *(const bf16x8*)(wt + (wn * 32 + lr) * 32 + fo);
            bf16x8 b1 = *(const bf16x8*)(wt + (wn * 32 + 16 + lr) * 32 + fo);
            const int g = (mi == 0 || mi == 3) ? 0 : (mi == 1 || mi == 4) ? 1 : (mi == 2) ? 2 : 3;
            const bf16x8* a = (mi < 3) ? ax : ah;
#pragma unroll
            for (int mf = 0; mf < 4; ++mf) {
                acc[g][mf][0] = __builtin_amdgcn_mfma_f32_16x16x32_bf16(a[mf], b0, acc[g][mf][0], 0, 0, 0);
                acc[g][mf][1] = __builtin_amdgcn_mfma_f32_16x16x32_bf16(a[mf], b1, acc[g][mf][1], 0, 0, 0);
            }
        }
    };
    auto WAITN = [&]() { asm volatile("s_waitcnt vmcnt(6) lgkmcnt(0)" ::: "memory"); };

    STAGE(0, 0);
#pragma unroll 1
    for (int kt = 0; kt < NT - 2; kt += 2) {
        STAGE(1, kt + 1); WAITN(); barrier_fence();
        COMPUTE(0);       barrier_fence();
        STAGE(0, kt + 2); WAITN(); barrier_fence();
        COMPUTE(1);       barrier_fence();
    }
    STAGE(1, NT - 1); WAITN(); barrier_fence();
    COMPUTE(0);       barrier_fence();
    asm volatile("s_waitcnt vmcnt(0) lgkmcnt(0)" ::: "memory");
    __builtin_amdgcn_s_barrier();
    asm volatile("" ::: "memory");
    COMPUTE(1);

#pragma unroll
    for (int nf = 0; nf < 2; ++nf) {
        const int gc = n0 + wn * 32 + nf * 16 + lr;
        const float br  = bih[gc];
        const float bz  = bih[HDIM + gc];
        const float bnx = bih[2 * HDIM + gc];
        const float bn2 = bun[gc];
#pragma unroll
        for (int mf = 0; mf < 4; ++mf) {
#pragma unroll
            for (int rr = 0; rr < 4; ++rr) {
                const int gr = m0 + wm * 64 + mf * 16 + ls * 4 + rr;
                const float rv = 1.f / (1.f + __expf(-(acc[0][mf][nf][rr] + br)));
                const float zv = 1.f / (1.f + __expf(-(acc[1][mf][nf][rr] + bz)));
                const float nv = tanhf(acc[2][mf][nf][rr] + bnx + rv * (acc[3][mf][nf][rr] + bn2));
                const float hv = hg[(size_t)gr * HDIM + gc];
                out[(size_t)gr * HDIM + gc] = (1.f - zv) * nv + zv * hv;
            }
        }
    }
}

extern "C" void kernel_launch(void* const* d_in, const int* in_sizes, int n_in,
                              void* d_out, int out_size, void* d_ws, size_t ws_size,
                              hipStream_t stream) {
    const float* x   = (const float*)d_in[0];
    const float* h   = (const float*)d_in[1];
    const float* Wih = (const float*)d_in[2];
    const float* bih = (const float*)d_in[3];
    const float* Ur  = (const float*)d_in[4];
    const float* Uz  = (const float*)d_in[5];
    const float* Un  = (const float*)d_in[6];
    const float* bun = (const float*)d_in[7];
    float* out = (float*)d_out;

    unsigned short* wsp  = (unsigned short*)d_ws;
    unsigned short* wihb = wsp;
    unsigned short* urb  = wihb + 3 * 1024 * 1024;
    unsigned short* uzb  = urb + 1024 * 1024;
    unsigned short* unb  = uzb + 1024 * 1024;
    unsigned short* xb   = unb + 1024 * 1024;
    unsigned short* hb   = xb + 8 * 1024 * 1024;

    const bool xhb = ws_size >= 46137344ull;  // 44 MB for bf16 weights + x + h

    cvt_all<<<xhb ? 22528 : 6144, 256, 0, stream>>>(
        x, h, Wih, Ur, Uz, Un, wihb, urb, uzb, unb, xb, hb);

    if (xhb) {
        gru_fused8<<<512, 512, 0, stream>>>(
            h, xb, hb, wihb, urb, uzb, unb, bih, bun, out);
    } else {
        dim3 grid(HDIM / BN, 8192 / 128);
        gru_fused_fb<<<grid, 256, 0, stream>>>(
            h, x, h, wihb, urb, uzb, unb, bih, bun, out);
    }
}

// Round 4
// 157.121 us; speedup vs baseline: 1.0043x; 1.0043x over previous
//
#include <hip/hip_runtime.h>
#include <hip/hip_bf16.h>
#include <cstdint>

#define HDIM 1024
#define NT 32   // K-tiles of 32

typedef __attribute__((ext_vector_type(8))) __bf16 bf16x8;
typedef __attribute__((ext_vector_type(8))) unsigned short u16x8;
typedef __attribute__((ext_vector_type(4))) float f32x4;
typedef __attribute__((ext_vector_type(16))) float f32x16;

static __device__ __forceinline__ unsigned short f2b(float f) {
    __hip_bfloat16 h = __float2bfloat16(f);
    return __builtin_bit_cast(unsigned short, h);
}

static __device__ __forceinline__ void barrier_fence() {
    asm volatile("" ::: "memory");
    __builtin_amdgcn_s_barrier();
    asm volatile("" ::: "memory");
}

// fp32 -> bf16 pack: weights (+ x,h when ws allows)
__global__ void __launch_bounds__(256) cvt_all(
    const float* __restrict__ x, const float* __restrict__ h,
    const float* __restrict__ wih, const float* __restrict__ ur,
    const float* __restrict__ uz, const float* __restrict__ un,
    unsigned short* __restrict__ wb, unsigned short* __restrict__ urb,
    unsigned short* __restrict__ uzb, unsigned short* __restrict__ unb,
    unsigned short* __restrict__ xb, unsigned short* __restrict__ hb) {
    int b = blockIdx.x;
    const float* src; unsigned short* dst; int idx;
    if (b < 3072)       { src = wih; dst = wb;  idx = b; }
    else if (b < 4096)  { src = ur;  dst = urb; idx = b - 3072; }
    else if (b < 5120)  { src = uz;  dst = uzb; idx = b - 4096; }
    else if (b < 6144)  { src = un;  dst = unb; idx = b - 5120; }
    else if (b < 14336) { src = x;   dst = xb;  idx = b - 6144; }
    else                { src = h;   dst = hb;  idx = b - 14336; }
    int i = idx * 256 + threadIdx.x;
    float4 v = ((const float4*)src)[i];
    ushort4 o;
    o.x = f2b(v.x); o.y = f2b(v.y); o.z = f2b(v.z); o.w = f2b(v.w);
    ((ushort4*)dst)[i] = o;
}

// R2 skeleton (4 waves, BM=128, BN=64, 2 blocks/CU, 2-barrier dbuf, vmcnt(10))
// upgraded to 32x32x16 MFMA + hoisted staging pointers + XCD swizzle.
// LDS per buffer (ushort): xs[0,4096) hs[4096,8192) w[mi]@8192+mi*2048.
// Swizzle: 16B slot s of row r at s ^ ((r>>1)&3), both sides.
__global__ void __launch_bounds__(256, 2)
gru32(const float* __restrict__ hg,
      const unsigned short* __restrict__ xb, const unsigned short* __restrict__ hb,
      const unsigned short* __restrict__ wih,
      const unsigned short* __restrict__ ur,
      const unsigned short* __restrict__ uz,
      const unsigned short* __restrict__ un,
      const float* __restrict__ bih, const float* __restrict__ bun,
      float* __restrict__ out) {
    __shared__ __align__(16) unsigned short smem[2][20480];

    const int tid  = threadIdx.x;
    const int lane = tid & 63;
    const int wv   = tid >> 6;      // 0..3
    const int wm   = wv >> 1;       // M half (64 rows)
    const int wn   = wv & 1;        // N half (32 cols)
    const int l31  = lane & 31;
    const int lh   = lane >> 5;     // k-octet half

    // XCD swizzle: 1024 blocks (64 M x 16 N), %8==0 -> simple bijective
    const int bid = blockIdx.x;
    const int swz = (bid & 7) * 128 + (bid >> 3);
    const int m0  = (swz & 63) * 128;
    const int n0  = (swz >> 6) * 64;

    // ---- persistent staging source pointers (advance 32 ush per K-tile)
    const int wr  = tid >> 2;                       // weight row 0..63
    const int wsl = (tid & 3) ^ ((tid >> 3) & 3);   // pre-swizzled slot
    const unsigned short* pw[6];
    pw[0] = wih + (size_t)(n0 + wr) * HDIM + wsl * 8;
    pw[1] = wih + (size_t)(HDIM + n0 + wr) * HDIM + wsl * 8;
    pw[2] = wih + (size_t)(2 * HDIM + n0 + wr) * HDIM + wsl * 8;
    pw[3] = ur  + (size_t)(n0 + wr) * HDIM + wsl * 8;
    pw[4] = uz  + (size_t)(n0 + wr) * HDIM + wsl * 8;
    pw[5] = un  + (size_t)(n0 + wr) * HDIM + wsl * 8;
    const unsigned short* pxh[4];
#pragma unroll
    for (int half = 0; half < 2; ++half) {
        const int c  = half * 256 + tid;            // 0..511
        const int r  = c >> 2;                      // row 0..127
        const int sl = (c & 3) ^ ((c >> 3) & 3);
        pxh[half]     = xb + (size_t)(m0 + r) * HDIM + sl * 8;
        pxh[2 + half] = hb + (size_t)(m0 + r) * HDIM + sl * 8;
    }

    // ---- loop-invariant ds_read lane offsets (ushort units)
    const int arow  = wm * 64 + l31;                // +32 per m-chunk (sel invariant)
    const int asel  = (arow >> 1) & 3;
    const int aoff0 = arow * 32 + ((0 + lh) ^ asel) * 8;   // kk=0
    const int aoff1 = arow * 32 + ((2 + lh) ^ asel) * 8;   // kk=1
    const int wrow  = wn * 32 + l31;
    const int bsel  = (wrow >> 1) & 3;
    const int boff0 = 8192 + wrow * 32 + ((0 + lh) ^ bsel) * 8;
    const int boff1 = 8192 + wrow * 32 + ((2 + lh) ^ bsel) * 8;

    f32x16 acc[4][2];   // [gate][m-chunk], 128 fp32 regs
#pragma unroll
    for (int g = 0; g < 4; ++g)
#pragma unroll
        for (int mc = 0; mc < 2; ++mc)
#pragma unroll
            for (int v = 0; v < 16; ++v)
                acc[g][mc][v] = 0.f;

    auto STAGE = [&](int bufi) {
        unsigned short* nb = &smem[bufi][0];
#pragma unroll
        for (int mi = 0; mi < 6; ++mi) {
            __builtin_amdgcn_global_load_lds(
                (const __attribute__((address_space(1))) void*)pw[mi],
                (__attribute__((address_space(3))) void*)(nb + 8192 + mi * 2048 + wv * 512),
                16, 0, 0);
            pw[mi] += 32;
        }
#pragma unroll
        for (int half = 0; half < 2; ++half) {
            __builtin_amdgcn_global_load_lds(
                (const __attribute__((address_space(1))) void*)pxh[half],
                (__attribute__((address_space(3))) void*)(nb + half * 2048 + wv * 512),
                16, 0, 0);
            pxh[half] += 32;
            __builtin_amdgcn_global_load_lds(
                (const __attribute__((address_space(1))) void*)pxh[2 + half],
                (__attribute__((address_space(3))) void*)(nb + 4096 + half * 2048 + wv * 512),
                16, 0, 0);
            pxh[2 + half] += 32;
        }
    };

    auto COMPUTE = [&](int bufi) {
        const unsigned short* sb = &smem[bufi][0];
        bf16x8 ax[2][2], ah[2][2];   // [m-chunk][kk]
#pragma unroll
        for (int mc = 0; mc < 2; ++mc) {
            ax[mc][0] = *(const bf16x8*)(sb + aoff0 + mc * 1024);
            ax[mc][1] = *(const bf16x8*)(sb + aoff1 + mc * 1024);
            ah[mc][0] = *(const bf16x8*)(sb + 4096 + aoff0 + mc * 1024);
            ah[mc][1] = *(const bf16x8*)(sb + 4096 + aoff1 + mc * 1024);
        }
#pragma unroll
        for (int mi = 0; mi < 6; ++mi) {
            bf16x8 b0 = *(const bf16x8*)(sb + boff0 + mi * 2048);
            bf16x8 b1 = *(const bf16x8*)(sb + boff1 + mi * 2048);
            const int g = (mi == 0 || mi == 3) ? 0 : (mi == 1 || mi == 4) ? 1 : (mi == 2) ? 2 : 3;
#pragma unroll
            for (int mc = 0; mc < 2; ++mc) {
                acc[g][mc] = __builtin_amdgcn_mfma_f32_32x32x16_bf16(
                    (mi < 3) ? ax[mc][0] : ah[mc][0], b0, acc[g][mc], 0, 0, 0);
                acc[g][mc] = __builtin_amdgcn_mfma_f32_32x32x16_bf16(
                    (mi < 3) ? ax[mc][1] : ah[mc][1], b1, acc[g][mc], 0, 0, 0);
            }
        }
    };

    auto WAITN = [&]() { asm volatile("s_waitcnt vmcnt(10)" ::: "memory"); };

    STAGE(0);
#pragma unroll 1
    for (int kt = 0; kt < NT - 2; kt += 2) {
        STAGE(1); WAITN(); barrier_fence();
        COMPUTE(0); barrier_fence();
        STAGE(0); WAITN(); barrier_fence();
        COMPUTE(1); barrier_fence();
    }
    STAGE(1); WAITN(); barrier_fence();
    COMPUTE(0); barrier_fence();
    asm volatile("s_waitcnt vmcnt(0) lgkmcnt(0)" ::: "memory");
    __builtin_amdgcn_s_barrier();
    asm volatile("" ::: "memory");
    COMPUTE(1);

    // epilogue (32x32 C/D: col=lane&31, row=(reg&3)+8*(reg>>2)+4*(lane>>5))
    const int gc = n0 + wn * 32 + l31;
    const float br  = bih[gc];
    const float bz  = bih[HDIM + gc];
    const float bnx = bih[2 * HDIM + gc];
    const float bn2 = bun[gc];
#pragma unroll
    for (int mc = 0; mc < 2; ++mc) {
#pragma unroll
        for (int v = 0; v < 16; ++v) {
            const int gr = m0 + wm * 64 + mc * 32 + (v & 3) + 8 * (v >> 2) + 4 * lh;
            const float rv = 1.f / (1.f + __expf(-(acc[0][mc][v] + br)));
            const float zv = 1.f / (1.f + __expf(-(acc[1][mc][v] + bz)));
            const float nv = tanhf(acc[2][mc][v] + bnx + rv * (acc[3][mc][v] + bn2));
            const float hv = hg[(size_t)gr * HDIM + gc];
            out[(size_t)gr * HDIM + gc] = (1.f - zv) * nv + zv * hv;
        }
    }
}

// ---------- fallback (ws too small for bf16 x/h): R2's proven 4-wave kernel ----------
__global__ void __launch_bounds__(256, 2)
gru_fused_fb(const float* __restrict__ hg,
             const float* __restrict__ xg32, const float* __restrict__ hg32,
             const unsigned short* __restrict__ wih,
             const unsigned short* __restrict__ ur,
             const unsigned short* __restrict__ uz,
             const unsigned short* __restrict__ un,
             const float* __restrict__ bih, const float* __restrict__ bun,
             float* __restrict__ out) {
    __shared__ __align__(16) unsigned short smem[2][20480];
    const int tid  = threadIdx.x;
    const int lane = tid & 63;
    const int wv   = tid >> 6;
    const int wm   = wv >> 1;
    const int wn   = wv & 1;
    const int lr   = lane & 15;
    const int ls   = lane >> 4;
    const int m0   = blockIdx.y * 128;
    const int n0   = blockIdx.x * 64;

    const unsigned short* wb6[6] = {
        wih + (size_t)n0 * HDIM, wih + (size_t)(HDIM + n0) * HDIM,
        wih + (size_t)(2 * HDIM + n0) * HDIM, ur + (size_t)n0 * HDIM,
        uz + (size_t)n0 * HDIM, un + (size_t)n0 * HDIM
    };
    const int wr  = tid >> 2;
    const int wsl = (tid & 3) ^ ((tid >> 3) & 3);

    f32x4 acc[4][4][2];
#pragma unroll
    for (int g = 0; g < 4; ++g)
#pragma unroll
        for (int mf = 0; mf < 4; ++mf)
#pragma unroll
            for (int nf = 0; nf < 2; ++nf)
                acc[g][mf][nf] = f32x4{0.f, 0.f, 0.f, 0.f};

    auto STAGE = [&](int bufi, int kt) {
        const int k0 = kt * 32;
        unsigned short* sb = &smem[bufi][0];
        float4 fx[2][2], fh[2][2];
#pragma unroll
        for (int half = 0; half < 2; ++half) {
            const int c2 = half * 256 + tid;
            const int r2 = c2 >> 2;
            const int sl = c2 & 3;
            const float* gx = xg32 + (size_t)(m0 + r2) * HDIM + k0 + sl * 8;
            const float* gh = hg32 + (size_t)(m0 + r2) * HDIM + k0 + sl * 8;
            fx[half][0] = ((const float4*)gx)[0];
            fx[half][1] = ((const float4*)gx)[1];
            fh[half][0] = ((const float4*)gh)[0];
            fh[half][1] = ((const float4*)gh)[1];
        }
#pragma unroll
        for (int mi = 0; mi < 6; ++mi) {
            const unsigned short* g = wb6[mi] + (size_t)wr * HDIM + k0 + wsl * 8;
            __builtin_amdgcn_global_load_lds(
                (const __attribute__((address_space(1))) void*)g,
                (__attribute__((address_space(3))) void*)(sb + 8192 + mi * 2048 + wv * 512),
                16, 0, 0);
        }
#pragma unroll
        for (int half = 0; half < 2; ++half) {
            const int c2 = half * 256 + tid;
            const int r2 = c2 >> 2;
            const int sp = (c2 & 3) ^ ((c2 >> 3) & 3);
            u16x8 px, ph;
#pragma unroll
            for (int q = 0; q < 4; ++q) {
                px[q]     = f2b(fx[half][0][q]);
                px[q + 4] = f2b(fx[half][1][q]);
                ph[q]     = f2b(fh[half][0][q]);
                ph[q + 4] = f2b(fh[half][1][q]);
            }
            *(u16x8*)(sb + r2 * 32 + sp * 8)        = px;
            *(u16x8*)(sb + 4096 + r2 * 32 + sp * 8) = ph;
        }
    };
    auto COMPUTE = [&](int bufi) {
        const unsigned short* sb = &smem[bufi][0];
        const int sel = (lr >> 1) & 3;
        const int fo  = (ls ^ sel) << 3;
        bf16x8 ax[4], ah[4];
#pragma unroll
        for (int mf = 0; mf < 4; ++mf) {
            const int row = wm * 64 + mf * 16 + lr;
            ax[mf] = *(const bf16x8*)(sb + row * 32 + fo);
            ah[mf] = *(const bf16x8*)(sb + 4096 + row * 32 + fo);
        }
#pragma unroll
        for (int mi = 0; mi < 6; ++mi) {
            const unsigned short* wt = sb + 8192 + mi * 2048;
            bf16x8 b0 = *(const bf16x8*)(wt + (wn * 32 + lr) * 32 + fo);
            bf16x8 b1 = *(const bf16x8*)(wt + (wn * 32 + 16 + lr) * 32 + fo);
            const int g = (mi == 0 || mi == 3) ? 0 : (mi == 1 || mi == 4) ? 1 : (mi == 2) ? 2 : 3;
            const bf16x8* a = (mi < 3) ? ax : ah;
#pragma unroll
            for (int mf = 0; mf < 4; ++mf) {
                acc[g][mf][0] = __builtin_amdgcn_mfma_f32_16x16x32_bf16(a[mf], b0, acc[g][mf][0], 0, 0, 0);
                acc[g][mf][1] = __builtin_amdgcn_mfma_f32_16x16x32_bf16(a[mf], b1, acc[g][mf][1], 0, 0, 0);
            }
        }
    };
    auto WAITN = [&]() { asm volatile("s_waitcnt vmcnt(6) lgkmcnt(0)" ::: "memory"); };

    STAGE(0, 0);
#pragma unroll 1
    for (int kt = 0; kt < NT - 2; kt += 2) {
        STAGE(1, kt + 1); WAITN(); barrier_fence();
        COMPUTE(0);       barrier_fence();
        STAGE(0, kt + 2); WAITN(); barrier_fence();
        COMPUTE(1);       barrier_fence();
    }
    STAGE(1, NT - 1); WAITN(); barrier_fence();
    COMPUTE(0);       barrier_fence();
    asm volatile("s_waitcnt vmcnt(0) lgkmcnt(0)" ::: "memory");
    __builtin_amdgcn_s_barrier();
    asm volatile("" ::: "memory");
    COMPUTE(1);

#pragma unroll
    for (int nf = 0; nf < 2; ++nf) {
        const int gc = n0 + wn * 32 + nf * 16 + lr;
        const float br  = bih[gc];
        const float bz  = bih[HDIM + gc];
        const float bnx = bih[2 * HDIM + gc];
        const float bn2 = bun[gc];
#pragma unroll
        for (int mf = 0; mf < 4; ++mf) {
#pragma unroll
            for (int rr = 0; rr < 4; ++rr) {
                const int gr = m0 + wm * 64 + mf * 16 + ls * 4 + rr;
                const float rv = 1.f / (1.f + __expf(-(acc[0][mf][nf][rr] + br)));
                const float zv = 1.f / (1.f + __expf(-(acc[1][mf][nf][rr] + bz)));
                const float nv = tanhf(acc[2][mf][nf][rr] + bnx + rv * (acc[3][mf][nf][rr] + bn2));
                const float hv = hg[(size_t)gr * HDIM + gc];
                out[(size_t)gr * HDIM + gc] = (1.f - zv) * nv + zv * hv;
            }
        }
    }
}

extern "C" void kernel_launch(void* const* d_in, const int* in_sizes, int n_in,
                              void* d_out, int out_size, void* d_ws, size_t ws_size,
                              hipStream_t stream) {
    const float* x   = (const float*)d_in[0];
    const float* h   = (const float*)d_in[1];
    const float* Wih = (const float*)d_in[2];
    const float* bih = (const float*)d_in[3];
    const float* Ur  = (const float*)d_in[4];
    const float* Uz  = (const float*)d_in[5];
    const float* Un  = (const float*)d_in[6];
    const float* bun = (const float*)d_in[7];
    float* out = (float*)d_out;

    unsigned short* wsp  = (unsigned short*)d_ws;
    unsigned short* wihb = wsp;
    unsigned short* urb  = wihb + 3 * 1024 * 1024;
    unsigned short* uzb  = urb + 1024 * 1024;
    unsigned short* unb  = uzb + 1024 * 1024;
    unsigned short* xb   = unb + 1024 * 1024;
    unsigned short* hb   = xb + 8 * 1024 * 1024;

    const bool xhb = ws_size >= 46137344ull;  // 44 MB for bf16 weights + x + h

    cvt_all<<<xhb ? 22528 : 6144, 256, 0, stream>>>(
        x, h, Wih, Ur, Uz, Un, wihb, urb, uzb, unb, xb, hb);

    if (xhb) {
        gru32<<<1024, 256, 0, stream>>>(
            h, xb, hb, wihb, urb, uzb, unb, bih, bun, out);
    } else {
        dim3 grid(HDIM / 64, 8192 / 128);
        gru_fused_fb<<<grid, 256, 0, stream>>>(
            h, x, h, wihb, urb, uzb, unb, bih, bun, out);
    }
}